// Round 4
// baseline (189.655 us; speedup 1.0000x reference)
//
#include <hip/hip_runtime.h>
#include <stdint.h>

// VQ-VAE nearest-codeword quantization, MI355X (gfx950).
// M=16384 rows, D=256 dims, K=8192 codewords.
// argmin_k ||x-c_k||^2 == argmin_k ( ||c_k||^2 - 2 x.c_k )
//
// R3: approx pass in fp8 e4m3 via mfma_scale_f32_16x16x128_f8f6f4 with
// unit scales (E8M0=127 -> 1.0): 2x the f16 MFMA rate, half the staging
// bytes and LDS reads. fp8 distance error sigma~1.6 (bound ~10) vs min-gap
// ~10 -> top-2 per 512-col split + EPS=12 fp64 rescore (machinery proven in
// R2) keeps the argmin exact. Distances packed as ((s+1024) bits &~511)|col9
// (+1024 guarantees positive -> uint order == float order; 9-bit mask
// perturbs <=0.13 << EPS; ties auto-break to smaller index).
//
// R1 lesson kept: XOR-swizzled 16B LDS chunks (bank-conflict-free, measured 0).
// R2 lesson kept: top-2/split candidates + rescore beats exact-GEMM FLOPs.

#define M_ROWS 16384
#define D_DIM  256
#define K_CB   8192
#define NSPLIT 16           // 512 codewords per split
#define BM 128
#define BN 128
#define EPS 12.0f

typedef float f32x4 __attribute__((ext_vector_type(4)));
typedef int   int4v __attribute__((ext_vector_type(4)));
typedef int   int8v __attribute__((ext_vector_type(8)));

__device__ __forceinline__ void gld_lds16(const void* g, void* l) {
  // async global->LDS, 16B/lane; LDS dest is wave-uniform base + lane*16.
  __builtin_amdgcn_global_load_lds((__attribute__((address_space(1))) void*)g,
                                   (__attribute__((address_space(3))) void*)l,
                                   16, 0, 0);
}

__device__ __forceinline__ uint32_t fp8x4(const f32x4 v) {
  // v_cvt_pk_fp8_f32: OCP e4m3 on gfx950; pack 4 floats -> 4 bytes
  int p = __builtin_amdgcn_cvt_pk_fp8_f32(v[0], v[1], 0, false);
  p = __builtin_amdgcn_cvt_pk_fp8_f32(v[2], v[3], p, true);
  return (uint32_t)p;
}

// ---- fused prep: x -> Ap fp8 (rows<4096 blocks) ; cb -> Bp fp8 + exact c2 ----
__global__ __launch_bounds__(256) void prep(const float* __restrict__ x,
                                            const float* __restrict__ cb,
                                            uint8_t* __restrict__ Ap,
                                            uint8_t* __restrict__ Bp,
                                            float* __restrict__ c2) {
  const int w = threadIdx.x >> 6, lane = threadIdx.x & 63;
  if (blockIdx.x < M_ROWS / 4) {
    const int row = blockIdx.x * 4 + w;                 // one wave per x row
    const f32x4 v = *(const f32x4*)(x + (size_t)row * D_DIM + lane * 4);
    *(uint32_t*)(Ap + (size_t)row * D_DIM + lane * 4) = fp8x4(v);
  } else {
    const int row = (blockIdx.x - M_ROWS / 4) * 4 + w;  // one wave per codeword
    const f32x4 v = *(const f32x4*)(cb + (size_t)row * D_DIM + lane * 4);
    *(uint32_t*)(Bp + (size_t)row * D_DIM + lane * 4) = fp8x4(v);
    double s = 0.0;
#pragma unroll
    for (int t = 0; t < 4; ++t) s += (double)v[t] * (double)v[t];
#pragma unroll
    for (int m = 1; m < 64; m <<= 1) s += __shfl_xor(s, m, 64);
    if (lane == 0) c2[row] = (float)s;                  // fp64-exact ||c||^2
  }
}

// swizzled fp8 fragment read: 32 contiguous logical bytes = 2 xor'd 16B chunks
__device__ __forceinline__ int8v frag8(const uint8_t* rowp, int fq, int x7) {
  const int4v lo = *(const int4v*)(rowp + (((fq * 2)     ^ x7) << 4));
  const int4v hi = *(const int4v*)(rowp + (((fq * 2 + 1) ^ x7) << 4));
  int8v r;
#pragma unroll
  for (int t = 0; t < 4; ++t) { r[t] = lo[t]; r[4 + t] = hi[t]; }
  return r;
}

// ---------------- main: fp8 K=256 GEMM + fused packed top-2 ----------------
__global__ __launch_bounds__(256, 3) void vq_main(const uint8_t* __restrict__ Ap,
                                                  const uint8_t* __restrict__ Bp,
                                                  const float* __restrict__ c2,
                                                  uint2* __restrict__ part) {
  __shared__ uint8_t As[BM * 128];    // 16 KB, chunk-swizzled (128B = k-half)
  __shared__ uint8_t Bs[BN * 128];    // 16 KB, chunk-swizzled
  __shared__ uint2 sred[BM * 2];      // cross-wn top-2 merge

  const int tid  = threadIdx.x;
  const int w    = tid >> 6;
  const int lane = tid & 63;
  const int wm   = w >> 1;            // 2x2 wave grid over the 128x128 tile
  const int wn   = w & 1;

  const int rowBase = blockIdx.x * BM;
  const int nBase   = blockIdx.y * (K_CB / NSPLIT);   // split base (512 cols)

  const int stRow  = lane >> 3;                  // staging: 8 lanes/row, 16B
  const int stColB = ((lane & 7) ^ stRow) * 16;  // swizzled logical byte offset

  const int fr = lane & 15;           // frag: m (or n) index
  const int fq = lane >> 4;           // frag: k-quarter (32 bytes each)
  const int x7 = fr & 7;

  // packed top-2 per accumulator row slot: ((s+1024) bits & ~511) | col9
  uint32_t t1[4][4], t2[4][4];
#pragma unroll
  for (int i = 0; i < 4; ++i)
#pragma unroll
    for (int r = 0; r < 4; ++r) { t1[i][r] = 0x7f7ffe00u; t2[i][r] = 0x7f7ffe00u; }

  for (int nit = 0; nit < (K_CB / NSPLIT) / BN; ++nit) {   // 4 codeword tiles
    f32x4 acc[4][4];
#pragma unroll
    for (int i = 0; i < 4; ++i)
#pragma unroll
      for (int j = 0; j < 4; ++j) acc[i][j] = (f32x4){0.f, 0.f, 0.f, 0.f};

#pragma unroll
    for (int kh = 0; kh < 2; ++kh) {                       // two k=128 halves
      const int kb = kh * 128;
#pragma unroll
      for (int ii = 0; ii < 4; ++ii) {                     // stage 32 A rows/wave
        const int rt = w * 32 + ii * 8 + stRow;
        gld_lds16(Ap + (size_t)(rowBase + rt) * D_DIM + kb + stColB,
                  As + rt * 128 + (lane & 7) * 16);        // phys = base+lane*16
      }
#pragma unroll
      for (int ii = 0; ii < 4; ++ii) {                     // and 32 B rows
        const int rt = w * 32 + ii * 8 + stRow;
        gld_lds16(Bp + (size_t)(nBase + nit * BN + rt) * D_DIM + kb + stColB,
                  Bs + rt * 128 + (lane & 7) * 16);
      }
      __syncthreads();
      int8v bf[4];
#pragma unroll
      for (int j = 0; j < 4; ++j)
        bf[j] = frag8(Bs + (wn * 64 + j * 16 + fr) * 128, fq, x7);
#pragma unroll
      for (int i = 0; i < 4; ++i) {
        const int8v av = frag8(As + (wm * 64 + i * 16 + fr) * 128, fq, x7);
#pragma unroll
        for (int j = 0; j < 4; ++j)
          acc[i][j] = __builtin_amdgcn_mfma_scale_f32_16x16x128_f8f6f4(
              av, bf[j], acc[i][j], 0, 0,          // cbsz=fp8, blgp=fp8
              0, 0x7f7f7f7f, 0, 0x7f7f7f7f);       // unit E8M0 scales
      }
      __syncthreads();
    }

    // epilogue: s = 1024 + c2[col] - 2*cross; pack; top-2 update (3 int ops).
#pragma unroll
    for (int j = 0; j < 4; ++j) {
      const int col9 = nit * BN + wn * 64 + j * 16 + fr;   // 0..511 within split
      const float cv = c2[nBase + col9] + 1024.0f;         // shift: s always > 0
#pragma unroll
      for (int i = 0; i < 4; ++i)
#pragma unroll
        for (int r = 0; r < 4; ++r) {
          const float s = fmaf(-2.0f, acc[i][j][r], cv);
          const uint32_t p = (__float_as_uint(s) & ~511u) | (uint32_t)col9;
          const uint32_t hi = t1[i][r] > p ? t1[i][r] : p;   // loser of (t1,p)
          t1[i][r] = t1[i][r] < p ? t1[i][r] : p;
          t2[i][r] = t2[i][r] < hi ? t2[i][r] : hi;
        }
    }
  }

  // merge packed top-2 across the 16 fr lanes sharing each row
#pragma unroll
  for (int i = 0; i < 4; ++i)
#pragma unroll
    for (int r = 0; r < 4; ++r) {
      uint32_t a1 = t1[i][r], a2 = t2[i][r];
#pragma unroll
      for (int m = 1; m < 16; m <<= 1) {
        const uint32_t o1 = __shfl_xor(a1, m, 64);
        const uint32_t o2 = __shfl_xor(a2, m, 64);
        const uint32_t hi = a1 > o1 ? a1 : o1;
        a1 = a1 < o1 ? a1 : o1;
        const uint32_t lo2 = a2 < o2 ? a2 : o2;
        a2 = lo2 < hi ? lo2 : hi;
      }
      if (fr == 0) {
        const int row = wm * 64 + i * 16 + fq * 4 + r;   // C/D layout (m89)
        sred[row * 2 + wn] = make_uint2(a1, a2);
      }
    }
  __syncthreads();
  if (tid < BM) {
    const uint2 a = sred[tid * 2 + 0], b = sred[tid * 2 + 1];
    const uint32_t hi = a.x > b.x ? a.x : b.x;
    const uint32_t m1 = a.x < b.x ? a.x : b.x;
    const uint32_t lo2 = a.y < b.y ? a.y : b.y;
    const uint32_t m2 = lo2 < hi ? lo2 : hi;
    part[(size_t)(rowBase + tid) * NSPLIT + blockIdx.y] = make_uint2(m1, m2);
  }
}

// -------- merge: 32 candidates/row -> certain winner or fp64 rescore --------
__global__ __launch_bounds__(256) void vq_merge(const uint2* __restrict__ part,
                                                const float* __restrict__ x,
                                                const float* __restrict__ cb,
                                                float* __restrict__ out) {
  const int w = threadIdx.x >> 6, lane = threadIdx.x & 63;
  const int row = blockIdx.x * 4 + w;                 // one wave per row

  uint32_t pk = 0x7f7ffe00u;
  int gidx = 0x7fffffff;
  if (lane < 32) {
    const uint2 pp = part[(size_t)row * NSPLIT + (lane >> 1)];
    pk = (lane & 1) ? pp.y : pp.x;
    gidx = (lane >> 1) * (K_CB / NSPLIT) + (int)(pk & 511u);
  }
  // integer min == numeric min (all packed values positive)
  uint32_t pmin = pk;
#pragma unroll
  for (int m = 1; m < 64; m <<= 1) {
    const uint32_t o = __shfl_xor(pmin, m, 64);
    pmin = pmin < o ? pmin : o;
  }
  const float vmin = __uint_as_float(pmin & ~511u);
  const float vme  = __uint_as_float(pk & ~511u);
  const unsigned long long mask = __ballot(lane < 32 && vme <= vmin + EPS);

  const f32x4 xv = *(const f32x4*)(x + (size_t)row * D_DIM + lane * 4);

  int winner;
  if (__popcll(mask) == 1) {
    winner = __shfl(gidx, __ffsll((long long)mask) - 1, 64);
  } else {
    // exact fp64 rescore of the qualifiers (ties -> smaller index, like np)
    double bestd = 1.0e300;
    int bidx = 0x7fffffff;
    unsigned long long mm = mask;
    while (mm) {
      const int q = __ffsll((long long)mm) - 1;
      mm &= mm - 1;
      const int ci = __shfl(gidx, q, 64);
      const f32x4 cv = *(const f32x4*)(cb + (size_t)ci * D_DIM + lane * 4);
      double s = 0.0;
#pragma unroll
      for (int t = 0; t < 4; ++t) {
        const double dx = (double)xv[t] - (double)cv[t];
        s += dx * dx;
      }
#pragma unroll
      for (int m = 1; m < 64; m <<= 1) s += __shfl_xor(s, m, 64);
      if (s < bestd || (s == bestd && ci < bidx)) { bestd = s; bidx = ci; }
    }
    winner = bidx;
  }

  float* out_recon = out;
  float* out_ze    = out + (size_t)M_ROWS * D_DIM;
  float* out_zq    = out + 2 * (size_t)M_ROWS * D_DIM;
  float* out_idx   = out + 3 * (size_t)M_ROWS * D_DIM;

  const f32x4 cv = *(const f32x4*)(cb + (size_t)winner * D_DIM + lane * 4);
  *(f32x4*)(out_recon + (size_t)row * D_DIM + lane * 4) = cv;  // identity decoder
  *(f32x4*)(out_zq    + (size_t)row * D_DIM + lane * 4) = cv;
  *(f32x4*)(out_ze    + (size_t)row * D_DIM + lane * 4) = xv;  // identity encoder
  if (lane == 0) out_idx[row] = (float)winner;
}

extern "C" void kernel_launch(void* const* d_in, const int* in_sizes, int n_in,
                              void* d_out, int out_size, void* d_ws, size_t ws_size,
                              hipStream_t stream) {
  const float* x  = (const float*)d_in[0];
  const float* cb = (const float*)d_in[1];
  float* out = (float*)d_out;

  // ws layout: c2 (32 KB) | part uint2[16384][16] (2 MB) | Ap fp8 (4 MB) | Bp fp8 (2 MB)
  char* ws = (char*)d_ws;
  float*    c2   = (float*)ws;
  uint2*    part = (uint2*)(ws + 32768);
  uint8_t*  Ap   = (uint8_t*)(ws + 32768 + 2097152);
  uint8_t*  Bp   = Ap + (size_t)M_ROWS * D_DIM;
  if (ws_size < (size_t)(32768 + 2097152 + 4194304 + 2097152)) return;

  prep    <<<dim3(M_ROWS / 4 + K_CB / 4), dim3(256), 0, stream>>>(x, cb, Ap, Bp, c2);
  vq_main <<<dim3(M_ROWS / BM, NSPLIT), dim3(256), 0, stream>>>(Ap, Bp, c2, part);
  vq_merge<<<dim3(M_ROWS / 4), dim3(256), 0, stream>>>(part, x, cb, out);
}